// Round 2
// baseline (12177.360 us; speedup 1.0000x reference)
//
#include <hip/hip_runtime.h>

// Problem constants (fixed by the reference)
#define BATCH 2048
#define TT    256
#define DD    128
#define HH    256
#define GG    768   // 3*H
#define PP    2048
#define RR    8     // batch rows per block (2048 rows / 256 CUs)
#define NTH   1024  // 16 waves per block, 1 block per CU

__device__ __forceinline__ float sigmoidf_(float v) { return 1.0f / (1.0f + expf(-v)); }

// Weight layouts tailored so the one-time register load is lane-coalesced:
//   wIHq[i][g][q][j] = w_ih[g*256+j][32*q + i]   (i<32)  -> flat ((i*3+g)*4+q)*256+j
//   wHHq[i][g][q][j] = w_hh[g*256+j][64*q + i]   (i<64)
//   pT[k][p]         = protos[p][k]
__global__ void prep_kernel(const float* __restrict__ w_ih, const float* __restrict__ w_hh,
                            const float* __restrict__ protos,
                            float* __restrict__ wIHq, float* __restrict__ wHHq,
                            float* __restrict__ pT) {
    int f = blockIdx.x * blockDim.x + threadIdx.x;
    if (f < 32 * 3 * 4 * 256) {
        int j = f & 255, u = f >> 8, q = u & 3, v = u >> 2, g = v % 3, i = v / 3;
        wIHq[f] = w_ih[(g * 256 + j) * DD + 32 * q + i];
    }
    if (f < 64 * 3 * 4 * 256) {
        int j = f & 255, u = f >> 8, q = u & 3, v = u >> 2, g = v % 3, i = v / 3;
        wHHq[f] = w_hh[(g * 256 + j) * HH + 64 * q + i];
    }
    if (f < HH * PP) {
        pT[f] = protos[(f & 2047) * HH + (f >> 11)];
    }
}

#define PART(s, r, q, j) ((((s) * 8 + (r)) * 4 + (q)) * 256 + (j))

__launch_bounds__(NTH, 4)
__global__ void gru_kernel(const float* __restrict__ x,
                           const float* __restrict__ wIHq, const float* __restrict__ wHHq,
                           const float* __restrict__ b_ih, const float* __restrict__ b_hh,
                           const float* __restrict__ pT,
                           int* __restrict__ out) {
    __shared__ float xs[2][DD][RR];      // 8 KB  x_t staging, k-major, double-buffered
    __shared__ float hs[HH][RR];         // 8 KB  hidden state, k-major
    __shared__ float part[4 * 8 * 4 * 256]; // 32 KB partial sums [stream][row][q][j]
    __shared__ float redv[16][RR];
    __shared__ int   redi[16][RR];

    const int tid  = threadIdx.x;
    const int j    = tid & 255;   // hidden unit
    const int wq   = tid >> 8;    // k-slice (uniform per 4-wave group -> uniform LDS addrs per wave)
    const int row0 = blockIdx.x * RR;

    // ---- one-time: weights into registers (fully coalesced, static-indexed) ----
    float wir[32], wiz[32], win[32];
    float whr[64], whz[64], whn[64];
    {
        const float* ih0 = wIHq + tid;  // ((i*3+g)<<10) + tid
        #pragma unroll
        for (int i = 0; i < 32; ++i) {
            wir[i] = ih0[(i * 3 + 0) << 10];
            wiz[i] = ih0[(i * 3 + 1) << 10];
            win[i] = ih0[(i * 3 + 2) << 10];
        }
        const float* hh0 = wHHq + tid;
        #pragma unroll
        for (int i = 0; i < 64; ++i) {
            whr[i] = hh0[(i * 3 + 0) << 10];
            whz[i] = hh0[(i * 3 + 1) << 10];
            whn[i] = hh0[(i * 3 + 2) << 10];
        }
    }
    const float bR  = b_ih[j] + b_hh[j];
    const float bZ  = b_ih[HH + j] + b_hh[HH + j];
    const float bXN = b_ih[2 * HH + j];
    const float bHN = b_hh[2 * HH + j];

    float hcur0 = 0.0f, hcur1 = 0.0f;   // rows 2*wq, 2*wq+1 for unit j
    { float2* hp = (float2*)&hs[j][2 * wq]; *hp = make_float2(0.0f, 0.0f); }

    // x loader mapping (first 4 waves): row lr, 4 cols at lk
    const int lr = tid >> 5;
    const int lk = (tid & 31) * 4;
    const float* xrow = x + (size_t)(row0 + lr) * TT * DD + lk;
    if (tid < 256) {
        float4 v = *(const float4*)(xrow);
        xs[0][lk + 0][lr] = v.x; xs[0][lk + 1][lr] = v.y;
        xs[0][lk + 2][lr] = v.z; xs[0][lk + 3][lr] = v.w;
    }
    __syncthreads();

    const float* xb0 = &xs[0][wq * 32][0];
    const float* xb1 = &xs[1][wq * 32][0];
    const float* hb  = &hs[wq * 64][0];

    for (int t = 0; t < TT; ++t) {
        const int cur = t & 1;

        // prefetch next x (in flight under the dot products)
        float4 pf;
        const bool havepf = (t + 1 < TT) && (tid < 256);
        if (havepf) pf = *(const float4*)(xrow + (size_t)(t + 1) * DD);

        float pr[8], pz[8], pxn[8], phn[8];
        #pragma unroll
        for (int r = 0; r < 8; ++r) { pr[r] = 0.f; pz[r] = 0.f; pxn[r] = 0.f; phn[r] = 0.f; }

        // ---- input-projection partials over my 32 k's (wave-uniform broadcast reads) ----
        const float* xb = cur ? xb1 : xb0;
        #pragma unroll
        for (int i = 0; i < 32; ++i) {
            const float w_r = wir[i], w_z = wiz[i], w_n = win[i];
            const float4 v0 = *(const float4*)(xb + i * 8);
            const float4 v1 = *(const float4*)(xb + i * 8 + 4);
            pr[0] += v0.x * w_r; pz[0] += v0.x * w_z; pxn[0] += v0.x * w_n;
            pr[1] += v0.y * w_r; pz[1] += v0.y * w_z; pxn[1] += v0.y * w_n;
            pr[2] += v0.z * w_r; pz[2] += v0.z * w_z; pxn[2] += v0.z * w_n;
            pr[3] += v0.w * w_r; pz[3] += v0.w * w_z; pxn[3] += v0.w * w_n;
            pr[4] += v1.x * w_r; pz[4] += v1.x * w_z; pxn[4] += v1.x * w_n;
            pr[5] += v1.y * w_r; pz[5] += v1.y * w_z; pxn[5] += v1.y * w_n;
            pr[6] += v1.z * w_r; pz[6] += v1.z * w_z; pxn[6] += v1.z * w_n;
            pr[7] += v1.w * w_r; pz[7] += v1.w * w_z; pxn[7] += v1.w * w_n;
        }
        // ---- hidden-projection partials over my 64 k's ----
        #pragma unroll
        for (int i = 0; i < 64; ++i) {
            const float w_r = whr[i], w_z = whz[i], w_n = whn[i];
            const float4 v0 = *(const float4*)(hb + i * 8);
            const float4 v1 = *(const float4*)(hb + i * 8 + 4);
            pr[0] += v0.x * w_r; pz[0] += v0.x * w_z; phn[0] += v0.x * w_n;
            pr[1] += v0.y * w_r; pz[1] += v0.y * w_z; phn[1] += v0.y * w_n;
            pr[2] += v0.z * w_r; pz[2] += v0.z * w_z; phn[2] += v0.z * w_n;
            pr[3] += v0.w * w_r; pz[3] += v0.w * w_z; phn[3] += v0.w * w_n;
            pr[4] += v1.x * w_r; pz[4] += v1.x * w_z; phn[4] += v1.x * w_n;
            pr[5] += v1.y * w_r; pz[5] += v1.y * w_z; phn[5] += v1.y * w_n;
            pr[6] += v1.z * w_r; pz[6] += v1.z * w_z; phn[6] += v1.z * w_n;
            pr[7] += v1.w * w_r; pz[7] += v1.w * w_z; phn[7] += v1.w * w_n;
        }

        // ---- publish partials (conflict-free: consecutive j within wave) ----
        #pragma unroll
        for (int r = 0; r < 8; ++r) {
            part[PART(0, r, wq, j)] = pr[r];
            part[PART(1, r, wq, j)] = pz[r];
            part[PART(2, r, wq, j)] = pxn[r];
            part[PART(3, r, wq, j)] = phn[r];
        }
        __syncthreads();   // A: all hs/xs reads + partial writes done

        // ---- gates for rows 2*wq, 2*wq+1 of unit j ----
        {
            const int r0 = 2 * wq;
            #pragma unroll
            for (int u = 0; u < 2; ++u) {
                const int r = r0 + u;
                const float sR  = part[PART(0, r, 0, j)] + part[PART(0, r, 1, j)]
                                + part[PART(0, r, 2, j)] + part[PART(0, r, 3, j)];
                const float sZ  = part[PART(1, r, 0, j)] + part[PART(1, r, 1, j)]
                                + part[PART(1, r, 2, j)] + part[PART(1, r, 3, j)];
                const float sXN = part[PART(2, r, 0, j)] + part[PART(2, r, 1, j)]
                                + part[PART(2, r, 2, j)] + part[PART(2, r, 3, j)];
                const float sHN = part[PART(3, r, 0, j)] + part[PART(3, r, 1, j)]
                                + part[PART(3, r, 2, j)] + part[PART(3, r, 3, j)];
                const float Rg = sigmoidf_(sR + bR);
                const float Zg = sigmoidf_(sZ + bZ);
                const float Ng = tanhf(sXN + bXN + Rg * (sHN + bHN));
                float& hc = u ? hcur1 : hcur0;
                hc = (1.0f - Zg) * Ng + Zg * hc;
            }
            float2* hp = (float2*)&hs[j][r0];
            *hp = make_float2(hcur0, hcur1);
        }
        if (havepf) {
            const int nxt = (t + 1) & 1;
            xs[nxt][lk + 0][lr] = pf.x; xs[nxt][lk + 1][lr] = pf.y;
            xs[nxt][lk + 2][lr] = pf.z; xs[nxt][lk + 3][lr] = pf.w;
        }
        __syncthreads();   // B: hs/xs ready for next step; part free for rewrite
    }

    // ---- cdist^2 + argmin: thread covers protos {tid, tid+1024} for all 8 rows ----
    float da[8], db[8];
    #pragma unroll
    for (int r = 0; r < 8; ++r) { da[r] = 0.f; db[r] = 0.f; }
    const float* pa = pT + tid;
    #pragma unroll 4
    for (int k = 0; k < HH; ++k) {
        const float va = pa[k * PP];
        const float vb = pa[k * PP + 1024];
        const float4 v0 = *(const float4*)&hs[k][0];
        const float4 v1 = *(const float4*)&hs[k][4];
        float d;
        d = v0.x - va; da[0] += d * d;  d = v0.x - vb; db[0] += d * d;
        d = v0.y - va; da[1] += d * d;  d = v0.y - vb; db[1] += d * d;
        d = v0.z - va; da[2] += d * d;  d = v0.z - vb; db[2] += d * d;
        d = v0.w - va; da[3] += d * d;  d = v0.w - vb; db[3] += d * d;
        d = v1.x - va; da[4] += d * d;  d = v1.x - vb; db[4] += d * d;
        d = v1.y - va; da[5] += d * d;  d = v1.y - vb; db[5] += d * d;
        d = v1.z - va; da[6] += d * d;  d = v1.z - vb; db[6] += d * d;
        d = v1.w - va; da[7] += d * d;  d = v1.w - vb; db[7] += d * d;
    }
    float bv[8]; int bi[8];
    #pragma unroll
    for (int r = 0; r < 8; ++r) {
        if (db[r] < da[r]) { bv[r] = db[r]; bi[r] = tid + 1024; }
        else               { bv[r] = da[r]; bi[r] = tid; }
    }
    // wave-level argmin (lowest-index tie-break), then cross-wave via LDS
    #pragma unroll
    for (int s = 1; s < 64; s <<= 1) {
        #pragma unroll
        for (int r = 0; r < 8; ++r) {
            const float ov = __shfl_xor(bv[r], s);
            const int   oi = __shfl_xor(bi[r], s);
            if (ov < bv[r] || (ov == bv[r] && oi < bi[r])) { bv[r] = ov; bi[r] = oi; }
        }
    }
    if ((tid & 63) == 0) {
        const int w = tid >> 6;
        #pragma unroll
        for (int r = 0; r < 8; ++r) { redv[w][r] = bv[r]; redi[w][r] = bi[r]; }
    }
    __syncthreads();
    if (tid < RR) {
        float v = redv[0][tid]; int idx = redi[0][tid];
        #pragma unroll
        for (int w = 1; w < 16; ++w) {
            const float ov = redv[w][tid]; const int oi = redi[w][tid];
            if (ov < v || (ov == v && oi < idx)) { v = ov; idx = oi; }
        }
        out[row0 + tid] = idx;
    }
}

extern "C" void kernel_launch(void* const* d_in, const int* in_sizes, int n_in,
                              void* d_out, int out_size, void* d_ws, size_t ws_size,
                              hipStream_t stream) {
    const float* x      = (const float*)d_in[0];
    const float* w_ih   = (const float*)d_in[1];
    const float* w_hh   = (const float*)d_in[2];
    const float* b_ih   = (const float*)d_in[3];
    const float* b_hh   = (const float*)d_in[4];
    const float* protos = (const float*)d_in[5];
    int* out = (int*)d_out;

    float* ws   = (float*)d_ws;
    float* wIHq = ws;                              // 98304 floats
    float* wHHq = ws + 32 * 3 * 4 * 256;           // 196608 floats
    float* pT   = ws + 32 * 3 * 4 * 256 + 64 * 3 * 4 * 256;  // 524288 floats

    hipLaunchKernelGGL(prep_kernel, dim3((HH * PP + 255) / 256), dim3(256), 0, stream,
                       w_ih, w_hh, protos, wIHq, wHHq, pT);
    hipLaunchKernelGGL(gru_kernel, dim3(BATCH / RR), dim3(NTH), 0, stream,
                       x, wIHq, wHHq, b_ih, b_hh, pT, out);
}